// Round 1
// baseline (2166.780 us; speedup 1.0000x reference)
//
#include <hip/hip_runtime.h>

#define BB 4
#define VV 50000
#define CC 128
#define KK 128
#define EE 400000
#define HH 128

#define CHUNK 512
#define NCHUNK 98      // ceil(VV/CHUNK)
#define PROJ_NCH 64
#define TILES_PER_B 1563  // ceil(VV/32)

__device__ __forceinline__ float tanh_fast(float u) {
    float uc = fminf(fmaxf(u, -15.f), 15.f);
    float e = __expf(-2.f * uc);
    return (1.f - e) / (1.f + e);
}

// ---------------- utility ----------------
__global__ void k_zero_u32(unsigned int* __restrict__ p, int n) {
    int i = blockIdx.x * blockDim.x + threadIdx.x;
    if (i < n) p[i] = 0u;
}

// ---------------- edge bucketing (counting sort by row) ----------------
__global__ void k_hist(const int* __restrict__ rows, int* __restrict__ hist) {
    int idx = blockIdx.x * blockDim.x + threadIdx.x;  // b*EE + e
    if (idx >= BB * EE) return;
    int b = idx / EE;
    atomicAdd(&hist[b * VV + rows[idx]], 1);
}

__global__ void k_scan1(const int* __restrict__ hist, int* __restrict__ rs,
                        int* __restrict__ csum) {
    int t = threadIdx.x;
    if (t >= BB * NCHUNK) return;
    int b = t / NCHUNK, ch = t % NCHUNK;
    int base = ch * CHUNK;
    int sum = 0;
    for (int i = 0; i < CHUNK; ++i) {
        int v = base + i;
        if (v >= VV) break;
        int h = hist[b * VV + v];
        rs[b * VV + v] = sum;
        sum += h;
    }
    csum[b * 128 + ch] = sum;
}

__global__ void k_scan2(int* __restrict__ csum) {
    int b = threadIdx.x;
    if (b >= BB) return;
    int run = 0;
    for (int ch = 0; ch < NCHUNK; ++ch) {
        int t = csum[b * 128 + ch];
        csum[b * 128 + ch] = run;
        run += t;
    }
}

__global__ void k_scan3(int* __restrict__ rs, const int* __restrict__ csum,
                        int* __restrict__ cursor) {
    int idx = blockIdx.x * blockDim.x + threadIdx.x;
    if (idx >= BB * VV) return;
    int b = idx / VV, v = idx % VV;
    int r = rs[idx] + csum[b * 128 + v / CHUNK];
    rs[idx] = r;
    cursor[idx] = r;
}

__global__ void k_bucket(const int* __restrict__ rows, int* __restrict__ cursor,
                         int* __restrict__ edge_idx) {
    int idx = blockIdx.x * blockDim.x + threadIdx.x;
    if (idx >= BB * EE) return;
    int b = idx / EE, e = idx % EE;
    int r = rows[idx];
    int p = atomicAdd(&cursor[b * VV + r], 1);
    edge_idx[(size_t)b * EE + p] = e;
}

// ---------------- stage A: spectral projection ----------------
// spec[b][k][c] = sum_v evecs[b][v][k] * mass[b][v] * x_in[b][v][c]
__global__ __launch_bounds__(256) void k_project(
        const float* __restrict__ x_in, const float* __restrict__ mass,
        const float* __restrict__ evecs, float* __restrict__ spec) {
    __shared__ float evs[8][128];
    __shared__ float xs[8][128];
    int b = blockIdx.x >> 6;
    int ch = blockIdx.x & 63;
    const int rowsPer = (VV + PROJ_NCH - 1) / PROJ_NCH;  // 782
    int vbase = ch * rowsPer;
    int vend = min(vbase + rowsPer, VV);
    int t = threadIdx.x;
    int tk = t >> 4, tc = t & 15;

    float acc[8][8];
#pragma unroll
    for (int i = 0; i < 8; ++i)
#pragma unroll
        for (int j = 0; j < 8; ++j) acc[i][j] = 0.f;

    int lrow = t >> 5;         // 0..7
    int lc4 = (t & 31) * 4;    // 0..124

    for (int v0 = vbase; v0 < vend; v0 += 8) {
        __syncthreads();
        int v = v0 + lrow;
        float4 ev4 = make_float4(0.f, 0.f, 0.f, 0.f);
        float4 xx4 = make_float4(0.f, 0.f, 0.f, 0.f);
        if (v < vend) {
            ev4 = *(const float4*)&evecs[((size_t)b * VV + v) * KK + lc4];
            float m = mass[b * VV + v];
            float4 xi = *(const float4*)&x_in[((size_t)b * VV + v) * CC + lc4];
            xx4 = make_float4(xi.x * m, xi.y * m, xi.z * m, xi.w * m);
        }
        *(float4*)&evs[lrow][lc4] = ev4;
        *(float4*)&xs[lrow][lc4] = xx4;
        __syncthreads();
#pragma unroll
        for (int vv = 0; vv < 8; ++vv) {
            float e[8], x[8];
            *(float4*)&e[0] = *(float4*)&evs[vv][tk * 8];
            *(float4*)&e[4] = *(float4*)&evs[vv][tk * 8 + 4];
            *(float4*)&x[0] = *(float4*)&xs[vv][tc * 8];
            *(float4*)&x[4] = *(float4*)&xs[vv][tc * 8 + 4];
#pragma unroll
            for (int i = 0; i < 8; ++i)
#pragma unroll
                for (int j = 0; j < 8; ++j)
                    acc[i][j] = fmaf(e[i], x[j], acc[i][j]);
        }
    }
#pragma unroll
    for (int i = 0; i < 8; ++i) {
        int k = tk * 8 + i;
#pragma unroll
        for (int j = 0; j < 8; ++j) {
            int c = tc * 8 + j;
            atomicAdd(&spec[((size_t)b * KK + k) * CC + c], acc[i][j]);
        }
    }
}

// ---------------- stage B: spectral decay ----------------
__global__ void k_decay(const float* __restrict__ spec, const float* __restrict__ evals,
                        const float* __restrict__ dt, float* __restrict__ spec_d) {
    int idx = blockIdx.x * blockDim.x + threadIdx.x;
    if (idx >= BB * KK * CC) return;
    int c = idx & 127;
    int k = (idx >> 7) & 127;
    int b = idx >> 14;
    float t = fmaxf(dt[c], 1e-8f);
    spec_d[idx] = spec[idx] * expf(-evals[b * KK + k] * t);
}

// ---------------- stage C: unproject ----------------
// xd[b][v][c] = sum_k evecs[b][v][k] * spec_d[b][k][c]
__global__ __launch_bounds__(256) void k_unproject(
        const float* __restrict__ evecs, const float* __restrict__ spec_d,
        float* __restrict__ xd) {
    __shared__ float ss[128][128];   // 64 KB
    __shared__ float evs[32][128];   // 16 KB
    int b = blockIdx.x / TILES_PER_B;
    int vbase = (blockIdx.x % TILES_PER_B) * 32;
    int t = threadIdx.x;

#pragma unroll
    for (int l = 0; l < 16; ++l) {
        int idx4 = l * 256 + t;
        int row = idx4 >> 5;
        int c4 = (idx4 & 31) * 4;
        *(float4*)&ss[row][c4] = *(const float4*)&spec_d[((size_t)b * KK + row) * CC + c4];
    }
#pragma unroll
    for (int l = 0; l < 4; ++l) {
        int idx4 = l * 256 + t;
        int row = idx4 >> 5;
        int c4 = (idx4 & 31) * 4;
        int v = vbase + row;
        float4 e4 = make_float4(0.f, 0.f, 0.f, 0.f);
        if (v < VV) e4 = *(const float4*)&evecs[((size_t)b * VV + v) * KK + c4];
        *(float4*)&evs[row][c4] = e4;
    }
    __syncthreads();

    int cg = t & 31, vg = t >> 5;
    int c4 = cg * 4;
    float acc[4][4];
#pragma unroll
    for (int i = 0; i < 4; ++i)
#pragma unroll
        for (int q = 0; q < 4; ++q) acc[i][q] = 0.f;

#pragma unroll 8
    for (int k = 0; k < 128; ++k) {
        float4 s = *(float4*)&ss[k][c4];
#pragma unroll
        for (int i = 0; i < 4; ++i) {
            float ev = evs[vg * 4 + i][k];
            acc[i][0] = fmaf(ev, s.x, acc[i][0]);
            acc[i][1] = fmaf(ev, s.y, acc[i][1]);
            acc[i][2] = fmaf(ev, s.z, acc[i][2]);
            acc[i][3] = fmaf(ev, s.w, acc[i][3]);
        }
    }
#pragma unroll
    for (int i = 0; i < 4; ++i) {
        int v = vbase + vg * 4 + i;
        if (v < VV) {
            float4 o = make_float4(acc[i][0], acc[i][1], acc[i][2], acc[i][3]);
            *(float4*)&xd[((size_t)b * VV + v) * CC + c4] = o;
        }
    }
}

// ---------------- stage D: row-gathered SpMM (gx, gy) ----------------
__global__ __launch_bounds__(256) void k_rowgather(
        const int* __restrict__ cols, const float* __restrict__ vxv,
        const float* __restrict__ vyv, const int* __restrict__ edge_idx,
        const int* __restrict__ rs, const int* __restrict__ cursor,
        const float* __restrict__ xd, float* __restrict__ gx, float* __restrict__ gy) {
    int w = blockIdx.x * 4 + (threadIdx.x >> 6);  // wave id == b*VV + v
    int lane = threadIdx.x & 63;
    int b = w / VV, v = w % VV;
    int beg = rs[w], end = cursor[w];
    float ax0 = 0.f, ax1 = 0.f, ay0 = 0.f, ay1 = 0.f;
    for (int i = beg; i < end; ++i) {
        int e = edge_idx[(size_t)b * EE + i];
        int col = cols[(size_t)b * EE + e];
        float fx = vxv[(size_t)b * EE + e];
        float fy = vyv[(size_t)b * EE + e];
        const float* src = &xd[((size_t)b * VV + col) * CC];
        float x0 = src[lane], x1 = src[lane + 64];
        ax0 = fmaf(fx, x0, ax0); ax1 = fmaf(fx, x1, ax1);
        ay0 = fmaf(fy, x0, ay0); ay1 = fmaf(fy, x1, ay1);
    }
    float* pgx = &gx[((size_t)b * VV + v) * CC];
    float* pgy = &gy[((size_t)b * VV + v) * CC];
    pgx[lane] = ax0; pgx[lane + 64] = ax1;
    pgy[lane] = ay0; pgy[lane + 64] = ay1;
}

// ---------------- stage E: spatial gradient features ----------------
__global__ __launch_bounds__(256) void k_gradfeat(
        const float* __restrict__ gx, const float* __restrict__ gy,
        const float* __restrict__ Are, const float* __restrict__ Aim,
        float* __restrict__ xgf) {
    __shared__ float As[128][36];
    __shared__ float Ais[128][36];
    __shared__ float gxs[32][132];
    __shared__ float gys[32][132];
    int b = blockIdx.x / TILES_PER_B;
    int vbase = (blockIdx.x % TILES_PER_B) * 32;
    int t = threadIdx.x;

#pragma unroll
    for (int l = 0; l < 4; ++l) {
        int idx4 = l * 256 + t;       // 1024 float4 = 32 rows x 128
        int row = idx4 >> 5;
        int c4 = (idx4 & 31) * 4;
        int v = vbase + row;
        float4 a = make_float4(0.f, 0.f, 0.f, 0.f), bb = a;
        if (v < VV) {
            a  = *(const float4*)&gx[((size_t)b * VV + v) * CC + c4];
            bb = *(const float4*)&gy[((size_t)b * VV + v) * CC + c4];
        }
        *(float4*)&gxs[row][c4] = a;
        *(float4*)&gys[row][c4] = bb;
    }

    int r = t >> 3;            // 0..31
    int c4l = (t & 7) * 4;     // 0..28
    int v = vbase + r;

    for (int cch = 0; cch < 4; ++cch) {
        int c0 = cch * 32;
        __syncthreads();
#pragma unroll
        for (int l = 0; l < 4; ++l) {
            int idx4 = l * 256 + t;   // 1024 float4 = 128j x 32c
            int j = idx4 >> 3;
            int cj4 = (idx4 & 7) * 4;
            *(float4*)&As[j][cj4]  = *(const float4*)&Are[(size_t)j * CC + c0 + cj4];
            *(float4*)&Ais[j][cj4] = *(const float4*)&Aim[(size_t)j * CC + c0 + cj4];
        }
        __syncthreads();

        float accRe[4] = {0.f, 0.f, 0.f, 0.f};
        float accIm[4] = {0.f, 0.f, 0.f, 0.f};
#pragma unroll 8
        for (int j = 0; j < 128; ++j) {
            float4 ar = *(float4*)&As[j][c4l];
            float4 ai = *(float4*)&Ais[j][c4l];
            float gxv = gxs[r][j], gyv = gys[r][j];
            accRe[0] = fmaf(gxv, ar.x, accRe[0]); accRe[0] = fmaf(-gyv, ai.x, accRe[0]);
            accRe[1] = fmaf(gxv, ar.y, accRe[1]); accRe[1] = fmaf(-gyv, ai.y, accRe[1]);
            accRe[2] = fmaf(gxv, ar.z, accRe[2]); accRe[2] = fmaf(-gyv, ai.z, accRe[2]);
            accRe[3] = fmaf(gxv, ar.w, accRe[3]); accRe[3] = fmaf(-gyv, ai.w, accRe[3]);
            accIm[0] = fmaf(gyv, ar.x, accIm[0]); accIm[0] = fmaf(gxv, ai.x, accIm[0]);
            accIm[1] = fmaf(gyv, ar.y, accIm[1]); accIm[1] = fmaf(gxv, ai.y, accIm[1]);
            accIm[2] = fmaf(gyv, ar.z, accIm[2]); accIm[2] = fmaf(gxv, ai.z, accIm[2]);
            accIm[3] = fmaf(gyv, ar.w, accIm[3]); accIm[3] = fmaf(gxv, ai.w, accIm[3]);
        }
        if (v < VV) {
            float4 o;
            float g0 = gxs[r][c0 + c4l + 0], h0 = gys[r][c0 + c4l + 0];
            float g1 = gxs[r][c0 + c4l + 1], h1 = gys[r][c0 + c4l + 1];
            float g2 = gxs[r][c0 + c4l + 2], h2 = gys[r][c0 + c4l + 2];
            float g3 = gxs[r][c0 + c4l + 3], h3 = gys[r][c0 + c4l + 3];
            o.x = tanh_fast(g0 * accRe[0] + h0 * accIm[0]);
            o.y = tanh_fast(g1 * accRe[1] + h1 * accIm[1]);
            o.z = tanh_fast(g2 * accRe[2] + h2 * accIm[2]);
            o.w = tanh_fast(g3 * accRe[3] + h3 * accIm[3]);
            *(float4*)&xgf[((size_t)b * VV + v) * CC + c0 + c4l] = o;
        }
    }
}

// ---------------- stage F: fused MLP + residual ----------------
__global__ __launch_bounds__(256) void k_mlp(
        const float* __restrict__ x_in, const float* __restrict__ xd,
        const float* __restrict__ xgf,
        const float* __restrict__ W0, const float* __restrict__ b0,
        const float* __restrict__ W1, const float* __restrict__ b1,
        float* __restrict__ out) {
    __shared__ float Ws[64][132];
    __shared__ float fs[32][68];
    __shared__ float hs[32][132];
    int b = blockIdx.x / TILES_PER_B;
    int vbase = (blockIdx.x % TILES_PER_B) * 32;
    int t = threadIdx.x;
    int cg = t & 31;    // output col group: cols cg*4..cg*4+3
    int rg = t >> 5;    // row group: rows rg*4..rg*4+3

    float acc[4][4];
#pragma unroll
    for (int i = 0; i < 4; ++i)
#pragma unroll
        for (int q = 0; q < 4; ++q) acc[i][q] = 0.f;

    const float* srcs[3] = {x_in, xd, xgf};
    for (int jc = 0; jc < 6; ++jc) {
        __syncthreads();
#pragma unroll
        for (int l = 0; l < 8; ++l) {
            int idx4 = l * 256 + t;     // 2048 float4 = 64j x 128h
            int jj = idx4 >> 5;
            int h4 = (idx4 & 31) * 4;
            *(float4*)&Ws[jj][h4] = *(const float4*)&W0[((size_t)(jc * 64 + jj)) * HH + h4];
        }
        const float* src = srcs[jc >> 1];
        int cbase = (jc & 1) * 64;
#pragma unroll
        for (int l = 0; l < 2; ++l) {
            int idx4 = l * 256 + t;     // 512 float4 = 32 rows x 64j
            int row = idx4 >> 4;
            int j4 = (idx4 & 15) * 4;
            int v = vbase + row;
            float4 f = make_float4(0.f, 0.f, 0.f, 0.f);
            if (v < VV) f = *(const float4*)&src[((size_t)b * VV + v) * CC + cbase + j4];
            *(float4*)&fs[row][j4] = f;
        }
        __syncthreads();
#pragma unroll 4
        for (int jj = 0; jj < 64; ++jj) {
            float4 w = *(float4*)&Ws[jj][cg * 4];
#pragma unroll
            for (int i = 0; i < 4; ++i) {
                float f = fs[rg * 4 + i][jj];
                acc[i][0] = fmaf(f, w.x, acc[i][0]);
                acc[i][1] = fmaf(f, w.y, acc[i][1]);
                acc[i][2] = fmaf(f, w.z, acc[i][2]);
                acc[i][3] = fmaf(f, w.w, acc[i][3]);
            }
        }
    }
    float4 bb0 = *(const float4*)&b0[cg * 4];
#pragma unroll
    for (int i = 0; i < 4; ++i) {
        int row = rg * 4 + i;
        float4 h4;
        h4.x = fmaxf(acc[i][0] + bb0.x, 0.f);
        h4.y = fmaxf(acc[i][1] + bb0.y, 0.f);
        h4.z = fmaxf(acc[i][2] + bb0.z, 0.f);
        h4.w = fmaxf(acc[i][3] + bb0.w, 0.f);
        *(float4*)&hs[row][cg * 4] = h4;
    }

    float acc2[4][4];
#pragma unroll
    for (int i = 0; i < 4; ++i)
#pragma unroll
        for (int q = 0; q < 4; ++q) acc2[i][q] = 0.f;

    for (int hc = 0; hc < 2; ++hc) {
        __syncthreads();
#pragma unroll
        for (int l = 0; l < 8; ++l) {
            int idx4 = l * 256 + t;
            int jj = idx4 >> 5;
            int c4 = (idx4 & 31) * 4;
            *(float4*)&Ws[jj][c4] = *(const float4*)&W1[((size_t)(hc * 64 + jj)) * CC + c4];
        }
        __syncthreads();
#pragma unroll 4
        for (int jj = 0; jj < 64; ++jj) {
            float4 w = *(float4*)&Ws[jj][cg * 4];
#pragma unroll
            for (int i = 0; i < 4; ++i) {
                float h = hs[rg * 4 + i][hc * 64 + jj];
                acc2[i][0] = fmaf(h, w.x, acc2[i][0]);
                acc2[i][1] = fmaf(h, w.y, acc2[i][1]);
                acc2[i][2] = fmaf(h, w.z, acc2[i][2]);
                acc2[i][3] = fmaf(h, w.w, acc2[i][3]);
            }
        }
    }
    float4 bb1 = *(const float4*)&b1[cg * 4];
#pragma unroll
    for (int i = 0; i < 4; ++i) {
        int v = vbase + rg * 4 + i;
        if (v < VV) {
            float4 xi = *(const float4*)&x_in[((size_t)b * VV + v) * CC + cg * 4];
            float4 o;
            o.x = acc2[i][0] + bb1.x + xi.x;
            o.y = acc2[i][1] + bb1.y + xi.y;
            o.z = acc2[i][2] + bb1.z + xi.z;
            o.w = acc2[i][3] + bb1.w + xi.w;
            *(float4*)&out[((size_t)b * VV + v) * CC + cg * 4] = o;
        }
    }
}

extern "C" void kernel_launch(void* const* d_in, const int* in_sizes, int n_in,
                              void* d_out, int out_size, void* d_ws, size_t ws_size,
                              hipStream_t stream) {
    (void)in_sizes; (void)n_in; (void)out_size; (void)ws_size;
    const float* x_in  = (const float*)d_in[0];
    const float* mass  = (const float*)d_in[1];
    const float* evals = (const float*)d_in[3];
    const float* evecs = (const float*)d_in[4];
    const int* grad_rows = (const int*)d_in[5];
    const int* grad_cols = (const int*)d_in[6];
    const float* gX = (const float*)d_in[7];
    const float* gY = (const float*)d_in[8];
    const float* dt  = (const float*)d_in[9];
    const float* Are = (const float*)d_in[10];
    const float* Aim = (const float*)d_in[11];
    const float* W0 = (const float*)d_in[12];
    const float* b0 = (const float*)d_in[13];
    const float* W1 = (const float*)d_in[14];
    const float* b1 = (const float*)d_in[15];
    float* out = (float*)d_out;

    char* w = (char*)d_ws;
    float* xd   = (float*)w; w += (size_t)BB * VV * CC * 4;
    float* gx   = (float*)w; w += (size_t)BB * VV * CC * 4;
    float* gy   = (float*)w; w += (size_t)BB * VV * CC * 4;
    float* spec   = (float*)w; w += (size_t)BB * KK * CC * 4;
    float* spec_d = (float*)w; w += (size_t)BB * KK * CC * 4;
    int* hist   = (int*)w; w += (size_t)BB * VV * 4;
    int* rs     = (int*)w; w += (size_t)BB * VV * 4;
    int* cursor = (int*)w; w += (size_t)BB * VV * 4;
    int* csum   = (int*)w; w += (size_t)BB * 128 * 4;
    int* edge_idx = (int*)w; w += (size_t)BB * EE * 4;
    float* xgf = gx;  // reuse gx buffer for tanh features (written per-row after reads)

    hipLaunchKernelGGL(k_zero_u32, dim3((BB * VV + 255) / 256), dim3(256), 0, stream,
                       (unsigned int*)hist, BB * VV);
    hipLaunchKernelGGL(k_zero_u32, dim3((BB * KK * CC + 255) / 256), dim3(256), 0, stream,
                       (unsigned int*)spec, BB * KK * CC);
    hipLaunchKernelGGL(k_hist, dim3((BB * EE + 255) / 256), dim3(256), 0, stream,
                       grad_rows, hist);
    hipLaunchKernelGGL(k_scan1, dim3(1), dim3(512), 0, stream, hist, rs, csum);
    hipLaunchKernelGGL(k_scan2, dim3(1), dim3(64), 0, stream, csum);
    hipLaunchKernelGGL(k_scan3, dim3((BB * VV + 255) / 256), dim3(256), 0, stream,
                       rs, csum, cursor);
    hipLaunchKernelGGL(k_bucket, dim3((BB * EE + 255) / 256), dim3(256), 0, stream,
                       grad_rows, cursor, edge_idx);
    hipLaunchKernelGGL(k_project, dim3(BB * PROJ_NCH), dim3(256), 0, stream,
                       x_in, mass, evecs, spec);
    hipLaunchKernelGGL(k_decay, dim3((BB * KK * CC + 255) / 256), dim3(256), 0, stream,
                       spec, evals, dt, spec_d);
    hipLaunchKernelGGL(k_unproject, dim3(BB * TILES_PER_B), dim3(256), 0, stream,
                       evecs, spec_d, xd);
    hipLaunchKernelGGL(k_rowgather, dim3(BB * VV / 4), dim3(256), 0, stream,
                       grad_cols, gX, gY, edge_idx, rs, cursor, xd, gx, gy);
    hipLaunchKernelGGL(k_gradfeat, dim3(BB * TILES_PER_B), dim3(256), 0, stream,
                       gx, gy, Are, Aim, xgf);
    hipLaunchKernelGGL(k_mlp, dim3(BB * TILES_PER_B), dim3(256), 0, stream,
                       x_in, xd, xgf, W0, b0, W1, b1, out);
}

// Round 2
// 1525.542 us; speedup vs baseline: 1.4203x; 1.4203x over previous
//
#include <hip/hip_runtime.h>

#define BB 4
#define VV 50000
#define CC 128
#define KK 128
#define EE 400000
#define HH 128

#define CHUNK 512
#define NCHUNK 98        // ceil(VV/CHUNK)
#define PROJ_NCH 64
#define TILES_PER_B 1563 // ceil(VV/32)  (unproject)
#define NT64 782         // ceil(VV/64)  (gradfeat / mlp)

typedef unsigned short u16;
typedef short bf16x8 __attribute__((ext_vector_type(8)));
typedef float f32x4 __attribute__((ext_vector_type(4)));

__device__ __forceinline__ u16 f2bf(float f) {
    union { float f; unsigned u; } x; x.f = f;
    unsigned r = x.u + 0x7FFFu + ((x.u >> 16) & 1u);
    return (u16)(r >> 16);
}
__device__ __forceinline__ float bf2f(u16 u) {
    union { unsigned u; float f; } x; x.u = ((unsigned)u) << 16;
    return x.f;
}
__device__ __forceinline__ unsigned pack2(float lo, float hi) {
    return ((unsigned)f2bf(hi) << 16) | (unsigned)f2bf(lo);
}
__device__ __forceinline__ float tanh_fast(float u) {
    float uc = fminf(fmaxf(u, -15.f), 15.f);
    float e = __expf(-2.f * uc);
    return (1.f - e) / (1.f + e);
}

// ---------------- utility ----------------
__global__ void k_zero_u32(unsigned int* __restrict__ p, int n) {
    int i = blockIdx.x * blockDim.x + threadIdx.x;
    if (i < n) p[i] = 0u;
}

// ---------------- edge bucketing (counting sort by row) ----------------
__global__ void k_hist(const int* __restrict__ rows, int* __restrict__ hist) {
    int idx = blockIdx.x * blockDim.x + threadIdx.x;
    if (idx >= BB * EE) return;
    int b = idx / EE;
    atomicAdd(&hist[b * VV + rows[idx]], 1);
}

__global__ void k_scan1(const int* __restrict__ hist, int* __restrict__ rs,
                        int* __restrict__ csum) {
    int t = threadIdx.x;
    if (t >= BB * NCHUNK) return;
    int b = t / NCHUNK, ch = t % NCHUNK;
    int base = ch * CHUNK;
    int sum = 0;
    for (int i = 0; i < CHUNK; ++i) {
        int v = base + i;
        if (v >= VV) break;
        int h = hist[b * VV + v];
        rs[b * VV + v] = sum;
        sum += h;
    }
    csum[b * 128 + ch] = sum;
}

__global__ void k_scan2(int* __restrict__ csum) {
    int b = threadIdx.x;
    if (b >= BB) return;
    int run = 0;
    for (int ch = 0; ch < NCHUNK; ++ch) {
        int t = csum[b * 128 + ch];
        csum[b * 128 + ch] = run;
        run += t;
    }
}

__global__ void k_scan3(int* __restrict__ rs, const int* __restrict__ csum,
                        int* __restrict__ cursor) {
    int idx = blockIdx.x * blockDim.x + threadIdx.x;
    if (idx >= BB * VV) return;
    int b = idx / VV, v = idx % VV;
    int r = rs[idx] + csum[b * 128 + v / CHUNK];
    rs[idx] = r;
    cursor[idx] = r;
}

__global__ void k_bucket(const int* __restrict__ rows, int* __restrict__ cursor,
                         int* __restrict__ edge_idx) {
    int idx = blockIdx.x * blockDim.x + threadIdx.x;
    if (idx >= BB * EE) return;
    int b = idx / EE, e = idx % EE;
    int r = rows[idx];
    int p = atomicAdd(&cursor[b * VV + r], 1);
    edge_idx[(size_t)b * EE + p] = e;
}

// ---------------- weight packing into MFMA B-fragment order ----------------
// B-frag layout (16x16x32): lane holds B[k = s*32 + (lane>>4)*8 + j][n = t*16 + (lane&15)]
// packed index: ((t*S + s)*64 + lane)*8 + j
__global__ void k_pack_rot(const float* __restrict__ Are, const float* __restrict__ Aim,
                           u16* __restrict__ Wre_p, u16* __restrict__ Wim_p) {
    int f = blockIdx.x * blockDim.x + threadIdx.x;  // 8t*8s*64 = 4096
    if (f >= 4096) return;
    int lane = f & 63;
    int s = (f >> 6) & 7;
    int t = f >> 9;
    int n = t * 16 + (lane & 15);
#pragma unroll
    for (int j = 0; j < 8; ++j) {
        int k = s * 32 + ((lane >> 4) << 3) + j;
        float re, im;
        if (k < 128) { re = Are[k * CC + n];           im = Aim[k * CC + n]; }
        else         { re = -Aim[(k - 128) * CC + n];  im = Are[(k - 128) * CC + n]; }
        Wre_p[(size_t)f * 8 + j] = f2bf(re);
        Wim_p[(size_t)f * 8 + j] = f2bf(im);
    }
}

__global__ void k_pack_w0(const float* __restrict__ W0, u16* __restrict__ W0p) {
    int f = blockIdx.x * blockDim.x + threadIdx.x;  // 8t*12s*64 = 6144
    if (f >= 6144) return;
    int lane = f & 63;
    int rem = f % 768;
    int s = rem >> 6;
    int t = f / 768;
    int n = t * 16 + (lane & 15);
#pragma unroll
    for (int j = 0; j < 8; ++j) {
        int k = s * 32 + ((lane >> 4) << 3) + j;
        W0p[(size_t)f * 8 + j] = f2bf(W0[(size_t)k * HH + n]);
    }
}

__global__ void k_pack_w1(const float* __restrict__ W1, u16* __restrict__ W1p) {
    int f = blockIdx.x * blockDim.x + threadIdx.x;  // 8t*4s*64 = 2048
    if (f >= 2048) return;
    int lane = f & 63;
    int s = (f >> 6) & 3;
    int t = f >> 8;
    int n = t * 16 + (lane & 15);
#pragma unroll
    for (int j = 0; j < 8; ++j) {
        int k = s * 32 + ((lane >> 4) << 3) + j;
        W1p[(size_t)f * 8 + j] = f2bf(W1[(size_t)k * CC + n]);
    }
}

// ---------------- stage A: spectral projection (fp32 vector) ----------------
__global__ __launch_bounds__(256) void k_project(
        const float* __restrict__ x_in, const float* __restrict__ mass,
        const float* __restrict__ evecs, float* __restrict__ spec) {
    __shared__ float evs[8][128];
    __shared__ float xs[8][128];
    int b = blockIdx.x >> 6;
    int ch = blockIdx.x & 63;
    const int rowsPer = (VV + PROJ_NCH - 1) / PROJ_NCH;  // 782
    int vbase = ch * rowsPer;
    int vend = min(vbase + rowsPer, VV);
    int t = threadIdx.x;
    int tk = t >> 4, tc = t & 15;

    float acc[8][8];
#pragma unroll
    for (int i = 0; i < 8; ++i)
#pragma unroll
        for (int j = 0; j < 8; ++j) acc[i][j] = 0.f;

    int lrow = t >> 5;
    int lc4 = (t & 31) * 4;

    for (int v0 = vbase; v0 < vend; v0 += 8) {
        __syncthreads();
        int v = v0 + lrow;
        float4 ev4 = make_float4(0.f, 0.f, 0.f, 0.f);
        float4 xx4 = make_float4(0.f, 0.f, 0.f, 0.f);
        if (v < vend) {
            ev4 = *(const float4*)&evecs[((size_t)b * VV + v) * KK + lc4];
            float m = mass[b * VV + v];
            float4 xi = *(const float4*)&x_in[((size_t)b * VV + v) * CC + lc4];
            xx4 = make_float4(xi.x * m, xi.y * m, xi.z * m, xi.w * m);
        }
        *(float4*)&evs[lrow][lc4] = ev4;
        *(float4*)&xs[lrow][lc4] = xx4;
        __syncthreads();
#pragma unroll
        for (int vv = 0; vv < 8; ++vv) {
            float e[8], x[8];
            *(float4*)&e[0] = *(float4*)&evs[vv][tk * 8];
            *(float4*)&e[4] = *(float4*)&evs[vv][tk * 8 + 4];
            *(float4*)&x[0] = *(float4*)&xs[vv][tc * 8];
            *(float4*)&x[4] = *(float4*)&xs[vv][tc * 8 + 4];
#pragma unroll
            for (int i = 0; i < 8; ++i)
#pragma unroll
                for (int j = 0; j < 8; ++j)
                    acc[i][j] = fmaf(e[i], x[j], acc[i][j]);
        }
    }
#pragma unroll
    for (int i = 0; i < 8; ++i) {
        int k = tk * 8 + i;
#pragma unroll
        for (int j = 0; j < 8; ++j) {
            int c = tc * 8 + j;
            atomicAdd(&spec[((size_t)b * KK + k) * CC + c], acc[i][j]);
        }
    }
}

// ---------------- stage B: spectral decay ----------------
__global__ void k_decay(const float* __restrict__ spec, const float* __restrict__ evals,
                        const float* __restrict__ dt, float* __restrict__ spec_d) {
    int idx = blockIdx.x * blockDim.x + threadIdx.x;
    if (idx >= BB * KK * CC) return;
    int c = idx & 127;
    int k = (idx >> 7) & 127;
    int b = idx >> 14;
    float t = fmaxf(dt[c], 1e-8f);
    spec_d[idx] = spec[idx] * expf(-evals[b * KK + k] * t);
}

// ---------------- stage C: unproject (fp32 compute, bf16 out) ----------------
__global__ __launch_bounds__(256) void k_unproject(
        const float* __restrict__ evecs, const float* __restrict__ spec_d,
        u16* __restrict__ xd) {
    __shared__ float ss[128][128];
    __shared__ float evs[32][128];
    int b = blockIdx.x / TILES_PER_B;
    int vbase = (blockIdx.x % TILES_PER_B) * 32;
    int t = threadIdx.x;

#pragma unroll
    for (int l = 0; l < 16; ++l) {
        int idx4 = l * 256 + t;
        int row = idx4 >> 5;
        int c4 = (idx4 & 31) * 4;
        *(float4*)&ss[row][c4] = *(const float4*)&spec_d[((size_t)b * KK + row) * CC + c4];
    }
#pragma unroll
    for (int l = 0; l < 4; ++l) {
        int idx4 = l * 256 + t;
        int row = idx4 >> 5;
        int c4 = (idx4 & 31) * 4;
        int v = vbase + row;
        float4 e4 = make_float4(0.f, 0.f, 0.f, 0.f);
        if (v < VV) e4 = *(const float4*)&evecs[((size_t)b * VV + v) * KK + c4];
        *(float4*)&evs[row][c4] = e4;
    }
    __syncthreads();

    int cg = t & 31, vg = t >> 5;
    int c4 = cg * 4;
    float acc[4][4];
#pragma unroll
    for (int i = 0; i < 4; ++i)
#pragma unroll
        for (int q = 0; q < 4; ++q) acc[i][q] = 0.f;

#pragma unroll 8
    for (int k = 0; k < 128; ++k) {
        float4 s = *(float4*)&ss[k][c4];
#pragma unroll
        for (int i = 0; i < 4; ++i) {
            float ev = evs[vg * 4 + i][k];
            acc[i][0] = fmaf(ev, s.x, acc[i][0]);
            acc[i][1] = fmaf(ev, s.y, acc[i][1]);
            acc[i][2] = fmaf(ev, s.z, acc[i][2]);
            acc[i][3] = fmaf(ev, s.w, acc[i][3]);
        }
    }
#pragma unroll
    for (int i = 0; i < 4; ++i) {
        int v = vbase + vg * 4 + i;
        if (v < VV) {
            uint2 o;
            o.x = pack2(acc[i][0], acc[i][1]);
            o.y = pack2(acc[i][2], acc[i][3]);
            *(uint2*)&xd[(((size_t)b * VV + v) << 7) + c4] = o;
        }
    }
}

// ---------------- stage D: row-gathered SpMM (bf16 xd -> bf16 gx,gy) -------
__global__ __launch_bounds__(256) void k_rowgather(
        const int* __restrict__ cols, const float* __restrict__ vxv,
        const float* __restrict__ vyv, const int* __restrict__ edge_idx,
        const int* __restrict__ rs, const int* __restrict__ cursor,
        const u16* __restrict__ xd, u16* __restrict__ gx, u16* __restrict__ gy) {
    int w = blockIdx.x * 4 + (threadIdx.x >> 6);
    int lane = threadIdx.x & 63;
    int b = w / VV;
    int beg = rs[w], end = cursor[w];
    float ax0 = 0.f, ax1 = 0.f, ay0 = 0.f, ay1 = 0.f;
    size_t ebase = (size_t)b * EE;
    for (int i = beg; i < end; ++i) {
        int e = edge_idx[ebase + i];
        int col = cols[ebase + e];
        float fx = vxv[ebase + e];
        float fy = vyv[ebase + e];
        unsigned u = *(const unsigned*)&xd[(((size_t)b * VV + col) << 7) + lane * 2];
        float x0 = bf2f((u16)(u & 0xFFFFu));
        float x1 = bf2f((u16)(u >> 16));
        ax0 = fmaf(fx, x0, ax0); ax1 = fmaf(fx, x1, ax1);
        ay0 = fmaf(fy, x0, ay0); ay1 = fmaf(fy, x1, ay1);
    }
    size_t ro = ((size_t)w << 7) + lane * 2;
    *(unsigned*)&gx[ro] = pack2(ax0, ax1);
    *(unsigned*)&gy[ro] = pack2(ay0, ay1);
}

// ---------------- stage E: spatial gradient features (MFMA bf16) -----------
__global__ __launch_bounds__(256) void k_gradfeat(
        const u16* __restrict__ gx, const u16* __restrict__ gy,
        const u16* __restrict__ Wre_p, const u16* __restrict__ Wim_p,
        u16* __restrict__ xgf) {
    __shared__ u16 Gs[64][264];     // [gx | gy] bf16, padded stride
    __shared__ u16 Bre[8][64][8];
    __shared__ u16 Bim[8][64][8];
    int b = blockIdx.x / NT64;
    int vbase = (blockIdx.x % NT64) * 64;
    int t = threadIdx.x;
    int lane = t & 63, w = t >> 6;
    {
        int row = t >> 2, p = t & 3;
        int v = vbase + row;
        bool ok = v < VV;
        size_t ro = ((size_t)b * VV + (ok ? v : 0)) << 7;
        const uint4* gxr = (const uint4*)&gx[ro + p * 32];
        const uint4* gyr = (const uint4*)&gy[ro + p * 32];
        uint4 z = make_uint4(0u, 0u, 0u, 0u);
#pragma unroll
        for (int i = 0; i < 4; ++i) {
            uint4 a = ok ? gxr[i] : z;
            uint4 c = ok ? gyr[i] : z;
            *(uint4*)&Gs[row][p * 32 + i * 8] = a;
            *(uint4*)&Gs[row][128 + p * 32 + i * 8] = c;
        }
    }
    __syncthreads();
    int m = lane & 15, q = lane >> 4;
    bf16x8 afr[8];
#pragma unroll
    for (int s = 0; s < 8; ++s)
        afr[s] = *(const bf16x8*)&Gs[w * 16 + m][s * 32 + q * 8];

    for (int tt = 0; tt < 8; ++tt) {
        __syncthreads();
        {
            const uint4* sre = (const uint4*)&Wre_p[(size_t)tt * 4096];
            const uint4* sim = (const uint4*)&Wim_p[(size_t)tt * 4096];
            uint4* dre = (uint4*)&Bre[0][0][0];
            uint4* dim = (uint4*)&Bim[0][0][0];
            dre[t] = sre[t]; dre[t + 256] = sre[t + 256];
            dim[t] = sim[t]; dim[t + 256] = sim[t + 256];
        }
        __syncthreads();
        f32x4 are = {0.f, 0.f, 0.f, 0.f};
        f32x4 aim = {0.f, 0.f, 0.f, 0.f};
#pragma unroll
        for (int s = 0; s < 8; ++s) {
            bf16x8 br = *(const bf16x8*)&Bre[s][lane][0];
            bf16x8 bi = *(const bf16x8*)&Bim[s][lane][0];
            are = __builtin_amdgcn_mfma_f32_16x16x32_bf16(afr[s], br, are, 0, 0, 0);
            aim = __builtin_amdgcn_mfma_f32_16x16x32_bf16(afr[s], bi, aim, 0, 0, 0);
        }
#pragma unroll
        for (int r = 0; r < 4; ++r) {
            int row = w * 16 + q * 4 + r;
            int v = vbase + row;
            if (v < VV) {
                float gxv = bf2f(Gs[row][tt * 16 + m]);
                float gyv = bf2f(Gs[row][128 + tt * 16 + m]);
                float u = gxv * are[r] + gyv * aim[r];
                xgf[(((size_t)b * VV + v) << 7) + tt * 16 + m] = f2bf(tanh_fast(u));
            }
        }
    }
}

// ---------------- stage F: fused MLP + residual (MFMA bf16) ----------------
__global__ __launch_bounds__(256) void k_mlp(
        const float* __restrict__ x_in, const u16* __restrict__ xd,
        const u16* __restrict__ xgf,
        const u16* __restrict__ W0p, const float* __restrict__ b0,
        const u16* __restrict__ W1p, const float* __restrict__ b1,
        float* __restrict__ out) {
    __shared__ u16 Fs[64][392];     // [x_in | xd | xgf] bf16, padded stride
    __shared__ u16 Hs[64][136];     // hidden, padded stride
    __shared__ u16 Bs[12][64][8];
    int b = blockIdx.x / NT64;
    int vbase = (blockIdx.x % NT64) * 64;
    int t = threadIdx.x;
    int lane = t & 63, w = t >> 6;
    {
        int row = t >> 2, p = t & 3;
        int v = vbase + row;
        bool ok = v < VV;
        size_t ro = ((size_t)b * VV + (ok ? v : 0)) << 7;
        const float4* xir = (const float4*)&x_in[ro + p * 32];
#pragma unroll
        for (int i = 0; i < 8; ++i) {
            float4 f = ok ? xir[i] : make_float4(0.f, 0.f, 0.f, 0.f);
            uint2 u;
            u.x = pack2(f.x, f.y);
            u.y = pack2(f.z, f.w);
            *(uint2*)&Fs[row][p * 32 + i * 4] = u;
        }
        const uint4* xdr = (const uint4*)&xd[ro + p * 32];
        const uint4* xgr = (const uint4*)&xgf[ro + p * 32];
        uint4 z = make_uint4(0u, 0u, 0u, 0u);
#pragma unroll
        for (int i = 0; i < 4; ++i) {
            uint4 a = ok ? xdr[i] : z;
            uint4 c = ok ? xgr[i] : z;
            *(uint4*)&Fs[row][128 + p * 32 + i * 8] = a;
            *(uint4*)&Fs[row][256 + p * 32 + i * 8] = c;
        }
    }
    __syncthreads();
    int m = lane & 15, q = lane >> 4;
    bf16x8 af[12];
#pragma unroll
    for (int s = 0; s < 12; ++s)
        af[s] = *(const bf16x8*)&Fs[w * 16 + m][s * 32 + q * 8];

    // GEMM1: feat @ W0 + b0 -> relu -> Hs
    for (int tt = 0; tt < 8; ++tt) {
        __syncthreads();
        {
            const uint4* src = (const uint4*)&W0p[(size_t)tt * 6144];
            uint4* d = (uint4*)&Bs[0][0][0];
            d[t] = src[t];
            d[t + 256] = src[t + 256];
            d[t + 512] = src[t + 512];
        }
        __syncthreads();
        f32x4 acc = {0.f, 0.f, 0.f, 0.f};
#pragma unroll
        for (int s = 0; s < 12; ++s) {
            bf16x8 bb = *(const bf16x8*)&Bs[s][lane][0];
            acc = __builtin_amdgcn_mfma_f32_16x16x32_bf16(af[s], bb, acc, 0, 0, 0);
        }
        float bias = b0[tt * 16 + m];
#pragma unroll
        for (int r = 0; r < 4; ++r) {
            Hs[w * 16 + q * 4 + r][tt * 16 + m] = f2bf(fmaxf(acc[r] + bias, 0.f));
        }
    }

    // GEMM2: h @ W1 + b1 + x_in -> out (A-frags from own wave's Hs rows)
    bf16x8 ah[4];
    for (int tt = 0; tt < 8; ++tt) {
        __syncthreads();
        {
            const uint4* src = (const uint4*)&W1p[(size_t)tt * 2048];
            uint4* d = (uint4*)&Bs[0][0][0];
            d[t] = src[t];
        }
        if (tt == 0) {
#pragma unroll
            for (int s = 0; s < 4; ++s)
                ah[s] = *(const bf16x8*)&Hs[w * 16 + m][s * 32 + q * 8];
        }
        __syncthreads();
        f32x4 acc = {0.f, 0.f, 0.f, 0.f};
#pragma unroll
        for (int s = 0; s < 4; ++s) {
            bf16x8 bb = *(const bf16x8*)&Bs[s][lane][0];
            acc = __builtin_amdgcn_mfma_f32_16x16x32_bf16(ah[s], bb, acc, 0, 0, 0);
        }
        float bias = b1[tt * 16 + m];
#pragma unroll
        for (int r = 0; r < 4; ++r) {
            int row = w * 16 + q * 4 + r;
            int v = vbase + row;
            if (v < VV) {
                size_t off = (((size_t)b * VV + v) << 7) + tt * 16 + m;
                out[off] = acc[r] + bias + x_in[off];
            }
        }
    }
}

extern "C" void kernel_launch(void* const* d_in, const int* in_sizes, int n_in,
                              void* d_out, int out_size, void* d_ws, size_t ws_size,
                              hipStream_t stream) {
    (void)in_sizes; (void)n_in; (void)out_size; (void)ws_size;
    const float* x_in  = (const float*)d_in[0];
    const float* mass  = (const float*)d_in[1];
    const float* evals = (const float*)d_in[3];
    const float* evecs = (const float*)d_in[4];
    const int* grad_rows = (const int*)d_in[5];
    const int* grad_cols = (const int*)d_in[6];
    const float* gX = (const float*)d_in[7];
    const float* gY = (const float*)d_in[8];
    const float* dt  = (const float*)d_in[9];
    const float* Are = (const float*)d_in[10];
    const float* Aim = (const float*)d_in[11];
    const float* W0 = (const float*)d_in[12];
    const float* b0 = (const float*)d_in[13];
    const float* W1 = (const float*)d_in[14];
    const float* b1 = (const float*)d_in[15];
    float* out = (float*)d_out;

    char* w = (char*)d_ws;
    u16* xd  = (u16*)w; w += (size_t)BB * VV * CC * 2;
    u16* gx  = (u16*)w; w += (size_t)BB * VV * CC * 2;
    u16* gy  = (u16*)w; w += (size_t)BB * VV * CC * 2;
    u16* xgf = (u16*)w; w += (size_t)BB * VV * CC * 2;
    float* spec   = (float*)w; w += (size_t)BB * KK * CC * 4;
    float* spec_d = (float*)w; w += (size_t)BB * KK * CC * 4;
    int* hist   = (int*)w; w += (size_t)BB * VV * 4;
    int* rs     = (int*)w; w += (size_t)BB * VV * 4;
    int* cursor = (int*)w; w += (size_t)BB * VV * 4;
    int* csum   = (int*)w; w += (size_t)BB * 128 * 4;
    int* edge_idx = (int*)w; w += (size_t)BB * EE * 4;
    u16* Wre_p = (u16*)w; w += (size_t)4096 * 8 * 2;
    u16* Wim_p = (u16*)w; w += (size_t)4096 * 8 * 2;
    u16* W0p   = (u16*)w; w += (size_t)6144 * 8 * 2;
    u16* W1p   = (u16*)w; w += (size_t)2048 * 8 * 2;

    hipLaunchKernelGGL(k_zero_u32, dim3((BB * VV + 255) / 256), dim3(256), 0, stream,
                       (unsigned int*)hist, BB * VV);
    hipLaunchKernelGGL(k_zero_u32, dim3((BB * KK * CC + 255) / 256), dim3(256), 0, stream,
                       (unsigned int*)spec, BB * KK * CC);
    hipLaunchKernelGGL(k_hist, dim3((BB * EE + 255) / 256), dim3(256), 0, stream,
                       grad_rows, hist);
    hipLaunchKernelGGL(k_scan1, dim3(1), dim3(512), 0, stream, hist, rs, csum);
    hipLaunchKernelGGL(k_scan2, dim3(1), dim3(64), 0, stream, csum);
    hipLaunchKernelGGL(k_scan3, dim3((BB * VV + 255) / 256), dim3(256), 0, stream,
                       rs, csum, cursor);
    hipLaunchKernelGGL(k_bucket, dim3((BB * EE + 255) / 256), dim3(256), 0, stream,
                       grad_rows, cursor, edge_idx);
    hipLaunchKernelGGL(k_pack_rot, dim3(16), dim3(256), 0, stream, Are, Aim, Wre_p, Wim_p);
    hipLaunchKernelGGL(k_pack_w0, dim3(24), dim3(256), 0, stream, W0, W0p);
    hipLaunchKernelGGL(k_pack_w1, dim3(8), dim3(256), 0, stream, W1, W1p);
    hipLaunchKernelGGL(k_project, dim3(BB * PROJ_NCH), dim3(256), 0, stream,
                       x_in, mass, evecs, spec);
    hipLaunchKernelGGL(k_decay, dim3((BB * KK * CC + 255) / 256), dim3(256), 0, stream,
                       spec, evals, dt, spec_d);
    hipLaunchKernelGGL(k_unproject, dim3(BB * TILES_PER_B), dim3(256), 0, stream,
                       evecs, spec_d, xd);
    hipLaunchKernelGGL(k_rowgather, dim3(BB * VV / 4), dim3(256), 0, stream,
                       grad_cols, gX, gY, edge_idx, rs, cursor, xd, gx, gy);
    hipLaunchKernelGGL(k_gradfeat, dim3(BB * NT64), dim3(256), 0, stream,
                       gx, gy, Wre_p, Wim_p, xgf);
    hipLaunchKernelGGL(k_mlp, dim3(BB * NT64), dim3(256), 0, stream,
                       x_in, xd, xgf, W0p, b0, W1p, b1, out);
}